// Round 1
// baseline (162.355 us; speedup 1.0000x reference)
//
#include <hip/hip_runtime.h>
#include <hip/hip_bf16.h>

// Problem constants (from reference): B=262144, D=256, S=16, C=10.
#define D_DIM 256
#define S_SYS 16
#define C_CLS 10

// ---------------- histogram: count samples per system ----------------
// hist layout: hist[t] stored at int index t*16 (64 B apart) to avoid
// same-line atomic contention across blocks.
__global__ __launch_bounds__(256) void hist_k(const int* __restrict__ sid, int n,
                                              int* __restrict__ hist) {
    __shared__ int lh[S_SYS];
    if (threadIdx.x < S_SYS) lh[threadIdx.x] = 0;
    __syncthreads();
    int i = blockIdx.x * 256 + threadIdx.x;
    if (i < n) atomicAdd(&lh[sid[i]], 1);
    __syncthreads();
    if (threadIdx.x < S_SYS) {
        int c = lh[threadIdx.x];
        if (c) atomicAdd(&hist[threadIdx.x * 16], c);
    }
}

// ---------------- exclusive scan over 16 bins ----------------
__global__ void scan_k(const int* __restrict__ hist, int* __restrict__ cursor) {
    if (threadIdx.x == 0 && blockIdx.x == 0) {
        int acc = 0;
        for (int t = 0; t < S_SYS; ++t) {
            cursor[t * 16] = acc;
            acc += hist[t * 16];
        }
    }
}

// ---------------- scatter: stable-ish counting sort of sample indices ----------------
// One atomicAdd per (block, sid) — block-aggregated to keep contention tiny.
// idx entry packs sid in top 4 bits: entry = i | (s << 28)  (B = 2^18 < 2^28).
__global__ __launch_bounds__(256) void scatter_k(const int* __restrict__ sid, int n,
                                                 int* __restrict__ cursor,
                                                 unsigned* __restrict__ idx) {
    __shared__ int wcnt[4][S_SYS];   // per-wave per-sid counts -> exclusive wave prefix
    __shared__ int bbase[S_SYS];     // block's base position per sid
    int i = blockIdx.x * 256 + threadIdx.x;
    int w = threadIdx.x >> 6;
    int lane = threadIdx.x & 63;
    int s = (i < n) ? sid[i] : -1;

    unsigned long long mym = 0;
    #pragma unroll 1
    for (int t = 0; t < S_SYS; ++t) {
        unsigned long long m = __ballot(s == t);
        if (lane == 0) wcnt[w][t] = (int)__popcll(m);
        if (s == t) mym = m;
    }
    int rank = (int)__popcll(mym & ((1ull << lane) - 1ull));
    __syncthreads();
    if (threadIdx.x < S_SYS) {
        int t = threadIdx.x, acc = 0;
        #pragma unroll
        for (int ww = 0; ww < 4; ++ww) { int c = wcnt[ww][t]; wcnt[ww][t] = acc; acc += c; }
        bbase[t] = atomicAdd(&cursor[t * 16], acc);
    }
    __syncthreads();
    if (i < n) {
        int pos = bbase[s] + wcnt[w][s] + rank;
        idx[pos] = (unsigned)i | ((unsigned)s << 28);
    }
}

// ---------------- main: 8 lanes per sample, sorted order ----------------
// Lane layout: group r = lane>>3 owns sample j = wave*8 + r; q = lane&7 owns
// float4 chunks q, q+8, ..., q+56 of the 256-elem row (full 128B line per group
// per load instruction -> perfect coalescing on the gathered rows).
// W loads are wave-uniform after the sort (same sid) -> broadcast, L1-hit.
__global__ __launch_bounds__(256) void main_k(const float* __restrict__ x,
                                              const float* __restrict__ W,
                                              const float* __restrict__ b,
                                              const unsigned* __restrict__ idx,
                                              float* __restrict__ out, int n) {
    int lane = threadIdx.x & 63;
    int r = lane >> 3, q = lane & 7;
    int wave = (int)((blockIdx.x * (unsigned)blockDim.x + threadIdx.x) >> 6);
    int j = wave * 8 + r;
    if (j >= n) return;
    unsigned e = idx[j];
    int i = (int)(e & 0x0FFFFFFFu);
    int s = (int)(e >> 28);

    const float4* __restrict__ xr = (const float4*)(x) + (size_t)i * (D_DIM / 4) + q;
    const float4* __restrict__ wr = (const float4*)(W) + (size_t)s * (C_CLS * D_DIM / 4) + q;

    float acc[C_CLS];
    #pragma unroll
    for (int c = 0; c < C_CLS; ++c) acc[c] = 0.f;

    #pragma unroll 2
    for (int k = 0; k < D_DIM / 4 / 8; ++k) {           // 8 iterations
        float4 xv = xr[k * 8];
        #pragma unroll
        for (int c = 0; c < C_CLS; ++c) {
            float4 wv = wr[c * (D_DIM / 4) + k * 8];
            acc[c] = fmaf(xv.x, wv.x,
                      fmaf(xv.y, wv.y,
                       fmaf(xv.z, wv.z,
                        fmaf(xv.w, wv.w, acc[c]))));
        }
    }

    // reduce each class across the 8-lane group (xor masks 1,2,4 stay in-group)
    #pragma unroll
    for (int c = 0; c < C_CLS; ++c) {
        acc[c] += __shfl_xor(acc[c], 1);
        acc[c] += __shfl_xor(acc[c], 2);
        acc[c] += __shfl_xor(acc[c], 4);
    }

    float* op = out + (size_t)i * C_CLS;
    op[q] = acc[q] + b[s * C_CLS + q];
    if (q < 2) op[8 + q] = acc[8 + q] + b[s * C_CLS + 8 + q];
}

// ---------------- fallback (if workspace too small): thread-per-sample ----------------
__global__ __launch_bounds__(256) void fallback_k(const float* __restrict__ x,
                                                  const int* __restrict__ sid,
                                                  const float* __restrict__ W,
                                                  const float* __restrict__ b,
                                                  float* __restrict__ out, int n) {
    int i = blockIdx.x * 256 + threadIdx.x;
    if (i >= n) return;
    int s = sid[i];
    const float4* xr = (const float4*)(x) + (size_t)i * (D_DIM / 4);
    const float4* wr = (const float4*)(W) + (size_t)s * (C_CLS * D_DIM / 4);
    float acc[C_CLS];
    #pragma unroll
    for (int c = 0; c < C_CLS; ++c) acc[c] = 0.f;
    for (int k = 0; k < D_DIM / 4; ++k) {
        float4 xv = xr[k];
        #pragma unroll
        for (int c = 0; c < C_CLS; ++c) {
            float4 wv = wr[c * (D_DIM / 4) + k];
            acc[c] = fmaf(xv.x, wv.x, fmaf(xv.y, wv.y, fmaf(xv.z, wv.z, fmaf(xv.w, wv.w, acc[c]))));
        }
    }
    #pragma unroll
    for (int c = 0; c < C_CLS; ++c) out[(size_t)i * C_CLS + c] = acc[c] + b[s * C_CLS + c];
}

extern "C" void kernel_launch(void* const* d_in, const int* in_sizes, int n_in,
                              void* d_out, int out_size, void* d_ws, size_t ws_size,
                              hipStream_t stream) {
    const float* x = (const float*)d_in[0];
    const int* sid = (const int*)d_in[1];
    const float* W = (const float*)d_in[2];
    const float* b = (const float*)d_in[3];
    float* out = (float*)d_out;
    const int n = in_sizes[1];   // B

    const size_t ws_needed = 2048 + (size_t)n * sizeof(unsigned);
    if (ws_size < ws_needed) {
        // Not enough scratch for the sort: correct-but-slower direct kernel.
        fallback_k<<<(n + 255) / 256, 256, 0, stream>>>(x, sid, W, b, out, n);
        return;
    }

    int* hist = (int*)d_ws;                 // 16 ints, 64B-strided  (bytes 0..1023)
    int* cursor = hist + 256;               // 16 ints, 64B-strided  (bytes 1024..2047)
    unsigned* idx = (unsigned*)((char*)d_ws + 2048);

    // zero hist+cursor every call (ws is poisoned once and never restored)
    hipMemsetAsync(d_ws, 0, 2048, stream);

    const int blocks256 = (n + 255) / 256;
    hist_k<<<blocks256, 256, 0, stream>>>(sid, n, hist);
    scan_k<<<1, 64, 0, stream>>>(hist, cursor);
    scatter_k<<<blocks256, 256, 0, stream>>>(sid, n, cursor, idx);

    // 8 samples per wave, 4 waves per block -> 32 samples/block
    const int main_blocks = (n + 31) / 32;
    main_k<<<main_blocks, 256, 0, stream>>>(x, W, b, idx, out, n);
}

// Round 2
// 148.409 us; speedup vs baseline: 1.0940x; 1.0940x over previous
//
#include <hip/hip_runtime.h>
#include <hip/hip_bf16.h>

// Problem constants (from reference): B=262144, D=256, S=16, C=10.
#define D_DIM 256
#define S_SYS 16
#define C_CLS 10
#define SPB   128   // samples per main-kernel block (bucket padding granule)
#define NB    4     // 8-sample batches per wave (32 samples/wave)

// ---------------- histogram: count samples per system ----------------
// hist[t] at int index t*16 (64 B apart) to avoid same-line atomic contention.
__global__ __launch_bounds__(256) void hist_k(const int* __restrict__ sid, int n,
                                              int* __restrict__ hist) {
    __shared__ int lh[S_SYS];
    if (threadIdx.x < S_SYS) lh[threadIdx.x] = 0;
    __syncthreads();
    int i = blockIdx.x * 256 + threadIdx.x;
    if (i < n) atomicAdd(&lh[sid[i]], 1);
    __syncthreads();
    if (threadIdx.x < S_SYS) {
        int c = lh[threadIdx.x];
        if (c) atomicAdd(&hist[threadIdx.x * 16], c);
    }
}

// ---------------- exclusive scan, PADDED to SPB multiples ----------------
// Every bucket starts at a multiple of SPB -> every main block is single-system.
__global__ void scan_k(const int* __restrict__ hist, int* __restrict__ cursor) {
    if (threadIdx.x == 0 && blockIdx.x == 0) {
        int acc = 0;
        for (int t = 0; t < S_SYS; ++t) {
            cursor[t * 16] = acc;
            int c = hist[t * 16];
            acc += ((c + SPB - 1) / SPB) * SPB;
        }
    }
}

// ---------------- scatter: counting sort of sample indices ----------------
// idx entry packs sid in top 4 bits: entry = i | (s << 28). Sentinel = 0xFFFFFFFF
// (cannot collide: i < 2^18). Gaps (padding) keep the pre-memset sentinel.
__global__ __launch_bounds__(256) void scatter_k(const int* __restrict__ sid, int n,
                                                 int* __restrict__ cursor,
                                                 unsigned* __restrict__ idx) {
    __shared__ int wcnt[4][S_SYS];
    __shared__ int bbase[S_SYS];
    int i = blockIdx.x * 256 + threadIdx.x;
    int w = threadIdx.x >> 6;
    int lane = threadIdx.x & 63;
    int s = (i < n) ? sid[i] : -1;

    unsigned long long mym = 0;
    #pragma unroll 1
    for (int t = 0; t < S_SYS; ++t) {
        unsigned long long m = __ballot(s == t);
        if (lane == 0) wcnt[w][t] = (int)__popcll(m);
        if (s == t) mym = m;
    }
    int rank = (int)__popcll(mym & ((1ull << lane) - 1ull));
    __syncthreads();
    if (threadIdx.x < S_SYS) {
        int t = threadIdx.x, acc = 0;
        #pragma unroll
        for (int ww = 0; ww < 4; ++ww) { int c = wcnt[ww][t]; wcnt[ww][t] = acc; acc += c; }
        bbase[t] = atomicAdd(&cursor[t * 16], acc);
    }
    __syncthreads();
    if (i < n) {
        int pos = bbase[s] + wcnt[w][s] + rank;
        idx[pos] = (unsigned)i | ((unsigned)s << 28);
    }
}

// ---------------- main: W[s] in LDS, deep x prefetch ----------------
// Block = 256 threads = 4 waves; each wave owns NB=4 batches of 8 samples.
// Lane (r,q): group r (lane>>3) works sample batch entries; q (lane&7) owns
// float4 chunk k*8+q of the 256-elem row -> each x load instr = 8 full 128B lines.
// All 32 x-loads per wave issue before compute (32 KB MLP/wave).
// W reads: ds_read_b128 at 8 unique 16B addrs, broadcast across groups -> conflict-free.
__global__ __launch_bounds__(256) void main2_k(const float* __restrict__ x,
                                               const float* __restrict__ W,
                                               const float* __restrict__ b,
                                               const unsigned* __restrict__ idx,
                                               float* __restrict__ out) {
    __shared__ float4 Wl[C_CLS * D_DIM / 4];   // 640 float4 = 10 KB
    const int tid = threadIdx.x;
    const long bpos = (long)blockIdx.x * SPB;
    const unsigned e0 = idx[bpos];             // first slot of a live block is always real
    if (e0 == 0xFFFFFFFFu) return;             // block beyond padded total
    const int s = (int)(e0 >> 28);

    const float4* __restrict__ Wg = (const float4*)W + (size_t)s * (C_CLS * D_DIM / 4);
    #pragma unroll
    for (int t = 0; t < 3; ++t) {
        int u = tid + t * 256;
        if (u < C_CLS * D_DIM / 4) Wl[u] = Wg[u];
    }
    __syncthreads();

    const int wv = tid >> 6, lane = tid & 63, r = lane >> 3, q = lane & 7;
    const long wpos = bpos + (long)wv * (8 * NB);

    unsigned e[NB]; int irow[NB];
    #pragma unroll
    for (int nb = 0; nb < NB; ++nb) {
        e[nb] = idx[wpos + nb * 8 + r];                       // broadcast across q-lanes
        irow[nb] = (e[nb] == 0xFFFFFFFFu) ? 0 : (int)(e[nb] & 0x0FFFFFFFu);
    }

    // ---- deep prefetch: all 32 x float4 loads in flight before compute ----
    const float4* __restrict__ xg = (const float4*)x;
    float4 xb[NB][8];
    #pragma unroll
    for (int nb = 0; nb < NB; ++nb) {
        const float4* xr = xg + (size_t)irow[nb] * (D_DIM / 4) + q;
        #pragma unroll
        for (int k = 0; k < 8; ++k) xb[nb][k] = xr[k * 8];
    }

    float acc[NB][C_CLS];
    #pragma unroll
    for (int nb = 0; nb < NB; ++nb)
        #pragma unroll
        for (int c = 0; c < C_CLS; ++c) acc[nb][c] = 0.f;

    #pragma unroll
    for (int k = 0; k < 8; ++k) {
        #pragma unroll
        for (int c = 0; c < C_CLS; ++c) {
            const float4 wvv = Wl[c * (D_DIM / 4) + k * 8 + q];
            #pragma unroll
            for (int nb = 0; nb < NB; ++nb) {
                acc[nb][c] = fmaf(xb[nb][k].x, wvv.x,
                             fmaf(xb[nb][k].y, wvv.y,
                              fmaf(xb[nb][k].z, wvv.z,
                               fmaf(xb[nb][k].w, wvv.w, acc[nb][c]))));
            }
        }
    }

    const float bq  = b[s * C_CLS + q];
    const float bq2 = (q < 2) ? b[s * C_CLS + 8 + q] : 0.f;

    #pragma unroll
    for (int nb = 0; nb < NB; ++nb) {
        float v0 = 0.f, v1 = 0.f;
        #pragma unroll
        for (int c = 0; c < C_CLS; ++c) {
            float v = acc[nb][c];
            v += __shfl_xor(v, 1);
            v += __shfl_xor(v, 2);
            v += __shfl_xor(v, 4);
            if (c == q)     v0 = v;   // compile-time index, runtime compare (no scratch)
            if (c == 8 + q) v1 = v;
        }
        if (e[nb] != 0xFFFFFFFFu) {
            float* op = out + (size_t)irow[nb] * C_CLS;
            op[q] = v0 + bq;
            if (q < 2) op[8 + q] = v1 + bq2;
        }
    }
}

// ---------------- fallback (workspace too small): thread-per-sample ----------------
__global__ __launch_bounds__(256) void fallback_k(const float* __restrict__ x,
                                                  const int* __restrict__ sid,
                                                  const float* __restrict__ W,
                                                  const float* __restrict__ b,
                                                  float* __restrict__ out, int n) {
    int i = blockIdx.x * 256 + threadIdx.x;
    if (i >= n) return;
    int s = sid[i];
    const float4* xr = (const float4*)(x) + (size_t)i * (D_DIM / 4);
    const float4* wr = (const float4*)(W) + (size_t)s * (C_CLS * D_DIM / 4);
    float acc[C_CLS];
    #pragma unroll
    for (int c = 0; c < C_CLS; ++c) acc[c] = 0.f;
    for (int k = 0; k < D_DIM / 4; ++k) {
        float4 xv = xr[k];
        #pragma unroll
        for (int c = 0; c < C_CLS; ++c) {
            float4 wv = wr[c * (D_DIM / 4) + k];
            acc[c] = fmaf(xv.x, wv.x, fmaf(xv.y, wv.y, fmaf(xv.z, wv.z, fmaf(xv.w, wv.w, acc[c]))));
        }
    }
    #pragma unroll
    for (int c = 0; c < C_CLS; ++c) out[(size_t)i * C_CLS + c] = acc[c] + b[s * C_CLS + c];
}

extern "C" void kernel_launch(void* const* d_in, const int* in_sizes, int n_in,
                              void* d_out, int out_size, void* d_ws, size_t ws_size,
                              hipStream_t stream) {
    const float* x = (const float*)d_in[0];
    const int* sid = (const int*)d_in[1];
    const float* W = (const float*)d_in[2];
    const float* b = (const float*)d_in[3];
    float* out = (float*)d_out;
    const int n = in_sizes[1];   // B

    const int nblk_main = (n + SPB - 1) / SPB + S_SYS;   // padded-bucket upper bound
    const size_t idx_entries = (size_t)nblk_main * SPB;
    const size_t ws_needed = 2048 + idx_entries * sizeof(unsigned);

    if (ws_size < ws_needed) {
        fallback_k<<<(n + 255) / 256, 256, 0, stream>>>(x, sid, W, b, out, n);
        return;
    }

    int* hist = (int*)d_ws;                 // 16 ints, 64B-strided (bytes 0..1023)
    int* cursor = hist + 256;               // 16 ints, 64B-strided (bytes 1024..2047)
    unsigned* idx = (unsigned*)((char*)d_ws + 2048);

    // ws is poisoned once and never restored between replays: re-init every call.
    hipMemsetAsync(d_ws, 0, 2048, stream);                       // hist + cursor = 0
    hipMemsetAsync(idx, 0xFF, idx_entries * sizeof(unsigned), stream);  // sentinel fill

    const int blocks256 = (n + 255) / 256;
    hist_k<<<blocks256, 256, 0, stream>>>(sid, n, hist);
    scan_k<<<1, 64, 0, stream>>>(hist, cursor);
    scatter_k<<<blocks256, 256, 0, stream>>>(sid, n, cursor, idx);
    main2_k<<<nblk_main, 256, 0, stream>>>(x, W, b, idx, out);
}